// Round 1
// baseline (1570.428 us; speedup 1.0000x reference)
//
#include <hip/hip_runtime.h>
#include <math.h>

#define BATCH 64
#define NPTS 10000
#define LATOMS 50
#define DIM 512
#define OUTD 7
#define KNEIGH 10

static __device__ __forceinline__ unsigned long long ullmin(unsigned long long a, unsigned long long b) {
    return a < b ? a : b;
}

// One block per (ligand atom l, batch b). Finds the 10 nearest vertices and sets mask bits.
__global__ __launch_bounds__(256) void topk_mask_kernel(
    const float* __restrict__ pos,   // [B, N, 3]
    const float* __restrict__ lig,   // [B, L, 3]
    unsigned char* __restrict__ mask // [B, N]
) {
    const int l = blockIdx.x;
    const int b = blockIdx.y;
    const int t = threadIdx.x;

    const float* posb = pos + (size_t)b * NPTS * 3;
    const float* lp = lig + ((size_t)b * LATOMS + l) * 3;
    const float lx = lp[0], ly = lp[1], lz = lp[2];

    // Per-thread sorted top-10 (ascending d2). Fully unrolled — stays in VGPRs.
    float bestd[KNEIGH];
    int besti[KNEIGH];
#pragma unroll
    for (int j = 0; j < KNEIGH; ++j) { bestd[j] = INFINITY; besti[j] = 0; }

    for (int n = t; n < NPTS; n += 256) {
        const float dx = posb[3 * n + 0] - lx;
        const float dy = posb[3 * n + 1] - ly;
        const float dz = posb[3 * n + 2] - lz;
        const float d2 = fmaf(dx, dx, fmaf(dy, dy, dz * dz));
        if (d2 < bestd[KNEIGH - 1]) {
            bool gt[KNEIGH];
#pragma unroll
            for (int j = 0; j < KNEIGH; ++j) gt[j] = (bestd[j] > d2);
#pragma unroll
            for (int j = KNEIGH - 1; j >= 1; --j) {
                if (gt[j - 1]) { bestd[j] = bestd[j - 1]; besti[j] = besti[j - 1]; }
            }
#pragma unroll
            for (int j = 0; j < KNEIGH; ++j) {
                const bool place = gt[j] && (j == 0 || !gt[j - 1]);
                if (place) { bestd[j] = d2; besti[j] = n; }
            }
        }
    }

    // Pack candidates as order-preserving 64-bit keys (d2 >= 0 so float bits are monotone).
    unsigned long long key[KNEIGH];
#pragma unroll
    for (int j = 0; j < KNEIGH; ++j) {
        key[j] = ((unsigned long long)__float_as_uint(bestd[j]) << 32) | (unsigned int)besti[j];
    }

    __shared__ unsigned long long s_red[4];
    __shared__ unsigned long long s_win;

    const int wave = t >> 6;
    const int lane = t & 63;

    for (int it = 0; it < KNEIGH; ++it) {
        unsigned long long m = key[0];
#pragma unroll
        for (int j = 1; j < KNEIGH; ++j) m = ullmin(m, key[j]);
        unsigned long long r = m;
#pragma unroll
        for (int off = 32; off > 0; off >>= 1) {
            unsigned long long o = __shfl_down(r, off, 64);
            r = ullmin(r, o);
        }
        if (lane == 0) s_red[wave] = r;
        __syncthreads();
        if (t == 0) {
            unsigned long long w = s_red[0];
            w = ullmin(w, s_red[1]);
            w = ullmin(w, s_red[2]);
            w = ullmin(w, s_red[3]);
            s_win = w;
            mask[(size_t)b * NPTS + (unsigned int)(w & 0xFFFFFFFFull)] = 1;
        }
        __syncthreads();
        const unsigned long long w = s_win;
#pragma unroll
        for (int j = 0; j < KNEIGH; ++j) {
            if (key[j] == w) key[j] = 0xFFFFFFFFFFFFFFFFull;
        }
    }
}

// One block per batch: compact mask -> index list, masked-mean pool of x,
// then the whole top_net (Linear -> LayerNorm -> SiLU -> Linear).
__global__ __launch_bounds__(512) void pool_mlp_kernel(
    const float* __restrict__ x,      // [B, N, D]
    const unsigned char* __restrict__ mask, // [B, N]
    const float* __restrict__ W1,     // [D, D]
    const float* __restrict__ b1,     // [D]
    const float* __restrict__ gamma,  // [D]
    const float* __restrict__ beta,   // [D]
    const float* __restrict__ W2,     // [D, O]
    const float* __restrict__ b2,     // [O]
    float* __restrict__ out           // [B, O]
) {
    const int b = blockIdx.x;
    const int t = threadIdx.x;
    const int wave = t >> 6;
    const int lane = t & 63;

    __shared__ int s_idx[LATOMS * KNEIGH]; // max 500 selected
    __shared__ int s_cnt;
    __shared__ float s_emb[DIM];
    __shared__ float s_h[DIM];
    __shared__ float s_s1[8], s_s2[8];

    if (t == 0) s_cnt = 0;
    __syncthreads();

    // Phase 1: compact mask into index list (order irrelevant for a sum).
    const unsigned char* mb = mask + (size_t)b * NPTS;
    for (int n = t; n < NPTS; n += 512) {
        if (mb[n]) {
            const int p = atomicAdd(&s_cnt, 1);
            s_idx[p] = n;
        }
    }
    __syncthreads();
    const int cnt = s_cnt;

    // Phase 2: gather + accumulate selected rows; thread t owns dimension t.
    const float* xb = x + (size_t)b * NPTS * DIM;
    float acc = 0.f;
    for (int i = 0; i < cnt; ++i) {
        acc += xb[(size_t)s_idx[i] * DIM + t];
    }
    const float emb = acc / (float)cnt;
    s_emb[t] = emb;
    __syncthreads();

    // Phase 3: h[t] = b1[t] + sum_k emb[k] * W1[k, t]  (W1 reads coalesced across threads)
    float h = b1[t];
    for (int k = 0; k < DIM; ++k) {
        h = fmaf(s_emb[k], W1[(size_t)k * DIM + t], h);
    }

    // Phase 4: LayerNorm over DIM, then SiLU.
    float s1 = h, s2 = h * h;
#pragma unroll
    for (int off = 32; off > 0; off >>= 1) {
        s1 += __shfl_down(s1, off, 64);
        s2 += __shfl_down(s2, off, 64);
    }
    if (lane == 0) { s_s1[wave] = s1; s_s2[wave] = s2; }
    __syncthreads();
    if (t == 0) {
        float a = 0.f, c = 0.f;
#pragma unroll
        for (int w = 0; w < 8; ++w) { a += s_s1[w]; c += s_s2[w]; }
        s_s1[0] = a; s_s2[0] = c;
    }
    __syncthreads();
    const float mu = s_s1[0] * (1.0f / DIM);
    const float var = s_s2[0] * (1.0f / DIM) - mu * mu;
    const float hn = (h - mu) * rsqrtf(var + 1e-5f) * gamma[t] + beta[t];
    const float sv = hn / (1.f + expf(-hn)); // SiLU
    s_h[t] = sv;
    __syncthreads();

    // Phase 5: out[b, o] = b2[o] + sum_d s_h[d] * W2[d, o]; wave o handles output o.
    if (wave < OUTD) {
        const int o = wave;
        float a = 0.f;
        for (int d = lane; d < DIM; d += 64) {
            a += s_h[d] * W2[(size_t)d * OUTD + o];
        }
#pragma unroll
        for (int off = 32; off > 0; off >>= 1) a += __shfl_down(a, off, 64);
        if (lane == 0) out[b * OUTD + o] = a + b2[o];
    }
}

extern "C" void kernel_launch(void* const* d_in, const int* in_sizes, int n_in,
                              void* d_out, int out_size, void* d_ws, size_t ws_size,
                              hipStream_t stream) {
    const float* pos   = (const float*)d_in[0];
    const float* x     = (const float*)d_in[1];
    const float* lig   = (const float*)d_in[2];
    const float* W1    = (const float*)d_in[3];
    const float* b1    = (const float*)d_in[4];
    const float* gamma = (const float*)d_in[5];
    const float* beta  = (const float*)d_in[6];
    const float* W2    = (const float*)d_in[7];
    const float* b2    = (const float*)d_in[8];
    float* out = (float*)d_out;

    unsigned char* mask = (unsigned char*)d_ws; // [B, N] bytes = 640 KB

    hipMemsetAsync(mask, 0, (size_t)BATCH * NPTS, stream);

    dim3 gridA(LATOMS, BATCH);
    topk_mask_kernel<<<gridA, 256, 0, stream>>>(pos, lig, mask);

    pool_mlp_kernel<<<BATCH, DIM, 0, stream>>>(x, mask, W1, b1, gamma, beta, W2, b2, out);
}